// Round 1
// 423.384 us; speedup vs baseline: 1.0009x; 1.0009x over previous
//
#include <hip/hip_runtime.h>
#include <math.h>

// Problem constants
#define B_ 8
#define N_ 5000
#define E_ 160000
#define M_ 40000      // N_*B_ rows, r = n*B_ + b
#define K_ 512
#define XT_ 313       // (M_+127)/128 row tiles

typedef __bf16 v8bf __attribute__((ext_vector_type(8)));
typedef float  v4f  __attribute__((ext_vector_type(4)));
typedef unsigned short u16x4v __attribute__((ext_vector_type(4)));
typedef unsigned short u16x8v __attribute__((ext_vector_type(8)));

__device__ __forceinline__ unsigned short f2b(float f){
  unsigned int u = __builtin_bit_cast(unsigned int, f);
  u += 0x7FFFu + ((u >> 16) & 1u);          // round-to-nearest-even
  return (unsigned short)(u >> 16);
}
__device__ __forceinline__ float b2f(unsigned short s){
  return __builtin_bit_cast(float, ((unsigned int)s) << 16);
}
__device__ __forceinline__ float softplus_(float x){
  // HW v_exp/v_log; x>15 -> x (exp overflow guard); bf16 output absorbs ~1e-6 err
  return (x > 15.0f) ? x : __logf(1.0f + __expf(x));
}
__device__ __forceinline__ float tanh_(float x){
  float e = __expf(2.0f*x);
  return 1.0f - 2.0f/(e + 1.0f);
}

// ---------------- setup kernels ----------------

__global__ __launch_bounds__(256) void zero_int2(int* a, int* b, int n){
  int i = blockIdx.x*256 + threadIdx.x;
  if (i < n){ a[i] = 0; b[i] = 0; }
}

// 5 * 131072 weight elems + 1024 packed bias. m: 0->WA, 1..4->Wall rows [Fc;Gc;Z;Fh]
__global__ __launch_bounds__(256) void convert_weights(
    const float* __restrict__ wA, const float* __restrict__ wFc,
    const float* __restrict__ wGc, const float* __restrict__ wZ,
    const float* __restrict__ wFh,
    const float* __restrict__ bFc, const float* __restrict__ bGc,
    const float* __restrict__ bZ,  const float* __restrict__ bFh,
    unsigned short* __restrict__ WA, unsigned short* __restrict__ Wall,
    float* __restrict__ biasP)
{
  int idx = blockIdx.x*256 + threadIdx.x;      // < 656384
  if (idx >= 655360){
    int j = idx - 655360;                      // 0..1023
    int mat = j >> 8, jj = j & 255;
    const float* bp = (mat == 0) ? bFc : (mat == 1) ? bGc : (mat == 2) ? bZ : bFh;
    biasP[j] = bp[jj];
    return;
  }
  int m = idx >> 17;                           // 131072 = 2^17
  int i = idx & 131071;
  float v;
  if      (m == 0) v = wA[i];
  else if (m == 1) v = wFc[i];
  else if (m == 2) v = wGc[i];
  else if (m == 3) v = wZ[i];
  else             v = wFh[i];
  unsigned short o = f2b(v);
  if (m == 0) WA[i] = o;
  else        Wall[(m-1)*131072 + i] = o;
}

// u (B,N,512) fp32 -> cB[r*256+q] bf16 (c part), hT[r*256+q] bf16 (h part), r=n*B+b
__global__ __launch_bounds__(256) void convert_u(
    const float* __restrict__ u, unsigned short* __restrict__ cB,
    unsigned short* __restrict__ hT)
{
  int r = blockIdx.x*4 + (threadIdx.x >> 6);
  int l = threadIdx.x & 63;
  int n = r >> 3, b = r & 7;
  const float* up = u + (size_t)(b*N_ + n)*512 + l*4;
  float4 cf = *(const float4*)up;
  float4 hf = *(const float4*)(up + 256);
  u16x4v c4, h4;
  c4.x = f2b(cf.x); c4.y = f2b(cf.y); c4.z = f2b(cf.z); c4.w = f2b(cf.w);
  h4.x = f2b(hf.x); h4.y = f2b(hf.y); h4.z = f2b(hf.z); h4.w = f2b(hf.w);
  *(u16x4v*)(cB + (size_t)r*256 + l*4) = c4;
  *(u16x4v*)(hT + (size_t)r*256 + l*4) = h4;
}

// ---------------- CSR build ----------------

__global__ __launch_bounds__(256) void hist_kernel(const int* __restrict__ dst, int* __restrict__ deg){
  int e = blockIdx.x*256 + threadIdx.x;   // exactly E_
  atomicAdd(&deg[dst[e]], 1);
}

__global__ __launch_bounds__(256) void scan_kernel(
    const int* __restrict__ deg, int* __restrict__ row_start, float* __restrict__ inv_deg)
{
  __shared__ int sums[256];
  int t = threadIdx.x;
  int base = t*20;
  int cnt[20];
  int local = 0;
#pragma unroll
  for (int i = 0; i < 20; ++i){
    int n = base + i;
    int d = (n < N_) ? deg[n] : 0;
    cnt[i] = d; local += d;
  }
  sums[t] = local; __syncthreads();
  for (int s = 1; s < 256; s <<= 1){
    int v = (t >= s) ? sums[t - s] : 0;
    __syncthreads();
    sums[t] += v;
    __syncthreads();
  }
  int prefix = (t == 0) ? 0 : sums[t-1];
#pragma unroll
  for (int i = 0; i < 20; ++i){
    int n = base + i;
    if (n < N_){
      row_start[n] = prefix;
      int d = cnt[i];
      inv_deg[n] = 1.0f / (float)((d > 1) ? d : 1);
      prefix += d;
    }
  }
  if (t == 255) row_start[N_] = prefix;
}

__global__ __launch_bounds__(256) void fill_kernel(
    const int* __restrict__ src, const int* __restrict__ dst,
    const int* __restrict__ row_start, int* __restrict__ cursor, int* __restrict__ csr)
{
  int e = blockIdx.x*256 + threadIdx.x;
  int d = dst[e];
  int p = atomicAdd(&cursor[d], 1);
  csr[row_start[d] + p] = src[e];
}

// one BLOCK per node n: 256 threads cover 8 batches x 32 col-segments.
// Per edge the whole block reads one contiguous 4 KB run of hT (rows s*8..s*8+7),
// csr[e] is a uniform scalar load. 2-edge unroll for memory-level parallelism.
__global__ __launch_bounds__(256) void gather_n_kernel(
    const unsigned short* __restrict__ hT, const int* __restrict__ csr,
    const int* __restrict__ row_start, const float* __restrict__ inv_deg,
    unsigned short* __restrict__ aggT)
{
  const int n = blockIdx.x;
  const int tid = threadIdx.x;
  const int boff = (tid >> 5)*256 + (tid & 31)*8;   // b*256 + cs*8 (shorts)
  const int e0 = row_start[n], e1 = row_start[n+1];

  float acc[8] = {};
  int e = e0;
  for (; e + 1 < e1; e += 2){
    int s0 = csr[e], s1 = csr[e+1];
    u16x8v v0 = *(const u16x8v*)(hT + (size_t)s0*2048 + boff);
    u16x8v v1 = *(const u16x8v*)(hT + (size_t)s1*2048 + boff);
#pragma unroll
    for (int i = 0; i < 8; ++i) acc[i] += b2f(v0[i]) + b2f(v1[i]);
  }
  if (e < e1){
    int s0 = csr[e];
    u16x8v v0 = *(const u16x8v*)(hT + (size_t)s0*2048 + boff);
#pragma unroll
    for (int i = 0; i < 8; ++i) acc[i] += b2f(v0[i]);
  }
  const float inv = inv_deg[n];
  u16x8v o;
#pragma unroll
  for (int i = 0; i < 8; ++i) o[i] = f2b(acc[i]*inv);
  *(u16x8v*)(aggT + (size_t)n*2048 + boff) = o;
}

// ---------------- tiled GEMM (2-phase pipelined, m230-V0 structure) ----------------
// C[m, n] = act( [A0|A1](m, 0:512) . Bw(n, 0:512) + bias[n] )
// 128x128 tile, 4 waves (2x2 of 64x64), BK=64, DOUBLE-BUFFERED global_load_lds
// staging with XOR-chunk swizzle on the GLOBAL address (LDS slots stay
// lane-contiguous as global_load_lds requires; fragment ds_read_b128 is
// bank-conflict-free).
// Pipeline (T3 minimum 2-phase): STAGE(next tile -> other buffer) is issued
// BEFORE the ds_read+MFMA of the current buffer; one vmcnt(0) + one raw
// s_barrier per K-step (vs the previous serial 2-barrier-with-drain version).
// Loads for tile k+1 are in flight under the MFMAs of tile k.
// 1-D grid, id decode groups all NY col-slab blocks of one row-tile x into a
// 64-id window with id % 8 == const -> same XCD under round-robin dispatch ->
// the A row-tile is fetched from HBM once and L2 serves the other NY-1 reads.
// MODE 0 (NY=2): gemm1 -> dst[r*256 + col], softplus.
// MODE 1 (NY=8): gemm_big -> act[(b*N+n)*1024 + col], tanh on slab y>>1==2.

__device__ __forceinline__ void stage_tile(
    const unsigned short* __restrict__ As, const unsigned short* __restrict__ Bw,
    int m0, int n0, int ak, int bk, int srow, int schunk, int w,
    unsigned short* lbase)
{
#pragma unroll
  for (int i = 0; i < 4; ++i){
    const unsigned short* gpA = As + (size_t)(m0 + i*32 + srow)*256 + ak + schunk*8;
    const unsigned short* gpB = Bw + (size_t)(n0 + i*32 + srow)*512 + bk + schunk*8;
    unsigned short* lpA = lbase + (i*32 + w*8)*64;
    unsigned short* lpB = lbase + 8192 + (i*32 + w*8)*64;
    __builtin_amdgcn_global_load_lds((const __attribute__((address_space(1))) void*)gpA,
                                     (__attribute__((address_space(3))) void*)lpA, 16, 0, 0);
    __builtin_amdgcn_global_load_lds((const __attribute__((address_space(1))) void*)gpB,
                                     (__attribute__((address_space(3))) void*)lpB, 16, 0, 0);
  }
}

__device__ __forceinline__ void compute_tile(
    const unsigned short* lA, const unsigned short* lB,
    int wr, int wc, int lq, int lr, v4f (&acc)[4][4])
{
#pragma unroll
  for (int ks = 0; ks < 2; ++ks){
    v8bf a[4], b[4];
#pragma unroll
    for (int rt = 0; rt < 4; ++rt){
      const int ar = wr*64 + rt*16 + lr;
      a[rt] = *(const v8bf*)(lA + ar*64 + (((ks*4 + lq) ^ (ar & 7)))*8);
    }
#pragma unroll
    for (int ct = 0; ct < 4; ++ct){
      const int br = wc*64 + ct*16 + lr;
      b[ct] = *(const v8bf*)(lB + br*64 + (((ks*4 + lq) ^ (br & 7)))*8);
    }
#pragma unroll
    for (int rt = 0; rt < 4; ++rt)
#pragma unroll
      for (int ct = 0; ct < 4; ++ct)
        acc[rt][ct] = __builtin_amdgcn_mfma_f32_16x16x32_bf16(a[rt], b[ct], acc[rt][ct], 0, 0, 0);
  }
}

template<int MODE>
__global__ __launch_bounds__(256) void gemm_tiled(
    const unsigned short* __restrict__ A0, const unsigned short* __restrict__ A1,
    const unsigned short* __restrict__ Bw, const float* __restrict__ bias,
    unsigned short* dstp)
{
  const int id = blockIdx.x;
  int x, y;
  if (MODE == 1){
    const int u6 = id & 63;
    y = u6 >> 3;
    x = (id >> 6)*8 + (u6 & 7);
  } else {
    const int u4 = id & 15;
    y = u4 >> 3;
    x = (id >> 4)*8 + (u4 & 7);
  }
  if (x >= XT_) return;

  // 64 KiB: two staging buffers, each {A 128x64 | B 128x64} bf16.
  // Epilogue repack (128x136 shorts = 34816 B) reuses the same array.
  __shared__ unsigned short lds[32768];

  const int tid = threadIdx.x;
  const int w  = tid >> 6, l = tid & 63;
  const int wr = w >> 1,  wc = w & 1;
  const int lq = l >> 4,  lr = l & 15;
  const int m0 = x * 128;
  const int n0 = y * 128;

  // staging: per issue of 32 rows, thread covers row (tid>>3),
  // fetching global 16B chunk ((tid&7) ^ (row&7)) into LDS slot (tid&7).
  const int srow   = tid >> 3;                 // 0..31
  const int schunk = (tid & 7) ^ (srow & 7);   // swizzled k-chunk

  v4f acc[4][4] = {};

  // prologue: stage K-tile 0 into buffer 0, drain, barrier.
  stage_tile(A0, Bw, m0, n0, 0, 0, srow, schunk, w, lds);
  asm volatile("s_waitcnt vmcnt(0)" ::: "memory");
  __builtin_amdgcn_s_barrier();

#pragma unroll 1
  for (int kb = 0; kb < 7; ++kb){
    const int kn = kb + 1;
    // issue next tile's loads into the other buffer (in flight under MFMA)
    stage_tile((kn < 4) ? A0 : A1, Bw, m0, n0, (kn & 3)*64, kn*64,
               srow, schunk, w, lds + ((kn & 1) << 14));
    // compute on current buffer
    {
      const unsigned short* lA = lds + ((kb & 1) << 14);
      compute_tile(lA, lA + 8192, wr, wc, lq, lr, acc);
    }
    // next tile's loads have landed under the MFMAs; one drain + one barrier.
    asm volatile("s_waitcnt vmcnt(0)" ::: "memory");
    __builtin_amdgcn_s_barrier();
  }
  // epilogue K-step: kb=7 lives in buffer 1
  compute_tile(lds + 16384, lds + 16384 + 8192, wr, wc, lq, lr, acc);

  float bv[4];
#pragma unroll
  for (int ct = 0; ct < 4; ++ct) bv[ct] = bias[n0 + wc*64 + ct*16 + lr];

  const bool is_tanh = (MODE == 1) && ((y >> 1) == 2);

  __syncthreads();   // done reading lds; reuse as output repack buffer
#pragma unroll
  for (int rt = 0; rt < 4; ++rt){
#pragma unroll
    for (int ct = 0; ct < 4; ++ct){
      const int col = wc*64 + ct*16 + lr;
#pragma unroll
      for (int reg = 0; reg < 4; ++reg){
        const int row = wr*64 + rt*16 + lq*4 + reg;
        const float xv = acc[rt][ct][reg] + bv[ct];
        const float v = is_tanh ? tanh_(xv) : softplus_(xv);
        lds[row*136 + col] = f2b(v);
      }
    }
  }
  __syncthreads();

  // coalesced store: 8 issues, each row gets 16 lanes x 16B = 256B contiguous
#pragma unroll
  for (int i = 0; i < 8; ++i){
    const int row = i*16 + (tid >> 4);
    const int r = m0 + row;
    if (r < M_){
      const uint4 v = *(const uint4*)(lds + row*136 + (tid & 15)*8);
      if (MODE == 0){
        *(uint4*)(dstp + (size_t)r*256 + n0 + (tid & 15)*8) = v;
      } else {
        const int n = r >> 3, b = r & 7;
        *(uint4*)(dstp + ((size_t)b*N_ + n)*1024 + n0 + (tid & 15)*8) = v;
      }
    }
  }
}

// ---------------- epilogue: dc with projection + dh ----------------
// One wave per row r. act aliases out (same row region) — reads complete before
// stores within the wave; no __restrict__ so the compiler keeps the order.

__global__ __launch_bounds__(256) void epilogue_kernel(
    const unsigned short* act, const float* __restrict__ u, float* out)
{
  int r = blockIdx.x*4 + (threadIdx.x >> 6);
  int l = threadIdx.x & 63;
  int n = r >> 3, b = r & 7;
  const size_t rr = (size_t)(b*N_ + n);
  const unsigned short* arow = act + rr*1024;
  const float* urow = u + rr*512;
  float* orow = out + rr*512;

  u16x4v fc4 = *(const u16x4v*)(arow +        l*4);
  u16x4v gc4 = *(const u16x4v*)(arow + 256 +  l*4);
  u16x4v z4  = *(const u16x4v*)(arow + 512 +  l*4);
  u16x4v fh4 = *(const u16x4v*)(arow + 768 +  l*4);
  float4 c4f = *(const float4*)(urow + l*4);
  float4 h4f = *(const float4*)(urow + 256 + l*4);

  float c[4] = {c4f.x, c4f.y, c4f.z, c4f.w};
  float h[4] = {h4f.x, h4f.y, h4f.z, h4f.w};
  float dc[4], fh[4];
  float num = 0.f, den = 0.f;
#pragma unroll
  for (int i = 0; i < 4; ++i){
    float fc = b2f(fc4[i]), gc = b2f(gc4[i]), z = b2f(z4[i]);
    fh[i] = b2f(fh4[i]);
    dc[i] = -fc*c[i] + gc*z;
    num += dc[i]*c[i];
    den += c[i]*c[i];
  }
#pragma unroll
  for (int s = 1; s < 64; s <<= 1){
    num += __shfl_xor(num, s, 64);
    den += __shfl_xor(den, s, 64);
  }
  const float proj = num / den;

  float4 o, oh;
  o.x = dc[0] - proj*c[0]; o.y = dc[1] - proj*c[1];
  o.z = dc[2] - proj*c[2]; o.w = dc[3] - proj*c[3];
  oh.x = -fh[0]*h[0]; oh.y = -fh[1]*h[1];
  oh.z = -fh[2]*h[2]; oh.w = -fh[3]*h[3];
  *(float4*)(orow + l*4) = o;
  *(float4*)(orow + 256 + l*4) = oh;
}

// ---------------- launch ----------------

extern "C" void kernel_launch(void* const* d_in, const int* in_sizes, int n_in,
                              void* d_out, int out_size, void* d_ws, size_t ws_size,
                              hipStream_t stream) {
  const float* u    = (const float*)d_in[0];
  const int*   src  = (const int*)d_in[1];
  const int*   dst  = (const int*)d_in[2];
  const float* wFc  = (const float*)d_in[4];
  const float* bFc  = (const float*)d_in[5];
  const float* wFh  = (const float*)d_in[6];
  const float* bFh  = (const float*)d_in[7];
  const float* wGc  = (const float*)d_in[8];
  const float* bGc  = (const float*)d_in[9];
  const float* wZ   = (const float*)d_in[10];
  const float* bZ   = (const float*)d_in[11];
  const float* wA   = (const float*)d_in[12];
  const float* bA   = (const float*)d_in[13];
  float* out = (float*)d_out;
  unsigned short* act = (unsigned short*)d_out;   // bf16 activations overlay out

  // ws layout. GEMM staging over-reads up to 64 rows past the end of
  // hT/cB/aggT/hB — each overflow lands in the NEXT allocation (readable garbage,
  // results discarded by the r < M_ store guard). Keep this buffer order.
  char* W = (char*)d_ws;
  unsigned short* hT   = (unsigned short*)(W + 0);           // 20,480,000 B
  unsigned short* cB   = (unsigned short*)(W + 20480000);
  unsigned short* aggT = (unsigned short*)(W + 40960000);
  unsigned short* hB   = (unsigned short*)(W + 61440000);
  unsigned short* WA   = (unsigned short*)(W + 81920000);    // 262,144 B
  unsigned short* Wall = (unsigned short*)(W + 82182144);    // 1,048,576 B
  float* biasP   = (float*)(W + 83230720);                   // 4,096 B
  int* deg       = (int*)(W + 83234816);
  int* row_start = (int*)(W + 83255296);
  int* cursor    = (int*)(W + 83275776);
  int* csr       = (int*)(W + 83296256);                     // 640,000 B
  float* inv_deg = (float*)(W + 83936256);

  zero_int2<<<(N_ + 255)/256, 256, 0, stream>>>(deg, cursor, N_);
  convert_weights<<<2564, 256, 0, stream>>>(wA, wFc, wGc, wZ, wFh,
                                            bFc, bGc, bZ, bFh, WA, Wall, biasP);
  convert_u<<<M_/4, 256, 0, stream>>>(u, cB, hT);
  hist_kernel<<<E_/256, 256, 0, stream>>>(dst, deg);
  scan_kernel<<<1, 256, 0, stream>>>(deg, row_start, inv_deg);
  fill_kernel<<<E_/256, 256, 0, stream>>>(src, dst, row_start, cursor, csr);
  gather_n_kernel<<<N_, 256, 0, stream>>>(hT, csr, row_start, inv_deg, aggT);

  // 1-D swizzled grids: 40 g-groups of 8 x-tiles (x<313 guard inside)
  gemm_tiled<0><<<40*16, 256, 0, stream>>>(hT, aggT, WA, bA, hB);
  gemm_tiled<1><<<40*64, 256, 0, stream>>>(cB, hB, Wall, biasP, act);

  epilogue_kernel<<<M_/4, 256, 0, stream>>>(act, u, out);
}

// Round 2
// 400.296 us; speedup vs baseline: 1.0586x; 1.0577x over previous
//
#include <hip/hip_runtime.h>
#include <math.h>

// Problem constants
#define B_ 8
#define N_ 5000
#define E_ 160000
#define M_ 40000      // N_*B_ rows, r = n*B_ + b
#define K_ 512
#define XT_ 313       // (M_+127)/128 row tiles

typedef __bf16 v8bf __attribute__((ext_vector_type(8)));
typedef float  v4f  __attribute__((ext_vector_type(4)));
typedef unsigned short u16x4v __attribute__((ext_vector_type(4)));
typedef unsigned short u16x8v __attribute__((ext_vector_type(8)));

__device__ __forceinline__ unsigned short f2b(float f){
  unsigned int u = __builtin_bit_cast(unsigned int, f);
  u += 0x7FFFu + ((u >> 16) & 1u);          // round-to-nearest-even
  return (unsigned short)(u >> 16);
}
__device__ __forceinline__ float b2f(unsigned short s){
  return __builtin_bit_cast(float, ((unsigned int)s) << 16);
}
__device__ __forceinline__ float softplus_(float x){
  // HW v_exp/v_log; x>15 -> x (exp overflow guard); bf16 output absorbs ~1e-6 err
  return (x > 15.0f) ? x : __logf(1.0f + __expf(x));
}
__device__ __forceinline__ float tanh_(float x){
  float e = __expf(2.0f*x);
  return 1.0f - 2.0f/(e + 1.0f);
}

// ---------------- setup kernels ----------------

__global__ __launch_bounds__(256) void zero_int2(int* a, int* b, int n){
  int i = blockIdx.x*256 + threadIdx.x;
  if (i < n){ a[i] = 0; b[i] = 0; }
}

// 5 * 131072 weight elems + 1024 packed bias. m: 0->WA, 1..4->Wall rows [Fc;Gc;Z;Fh]
// B matrices are written in a REGISTER-FRAGMENT-PACKED layout so the GEMM can
// load its MFMA B-fragments directly from L2 with perfectly coalesced 1 KB
// wave loads (no LDS round-trip for B):
//   pidx(n,col): y=n>>7, nn=n&127, cb=nn>>4, lr=nn&15,
//                kb=col>>6, ch=(col&63)>>3, e=col&7, ks=ch>>2, lq=ch&3,
//                lane=lq*16+lr
//   pidx = ((((y*8+kb)*2+ks)*8+cb)*64+lane)*8+e
// In the GEMM, wave (wc), fragment (ks,ct), lane l reads
//   Bp[((((y*8+kb)*2+ks)*8+wc*4+ct)*64+l)*8 .. +7]
// which equals Bw[n0 + wc*64+ct*16+(l&15)][kb*64+(ks*4+(l>>4))*8 + 0..7].
__global__ __launch_bounds__(256) void convert_weights(
    const float* __restrict__ wA, const float* __restrict__ wFc,
    const float* __restrict__ wGc, const float* __restrict__ wZ,
    const float* __restrict__ wFh,
    const float* __restrict__ bFc, const float* __restrict__ bGc,
    const float* __restrict__ bZ,  const float* __restrict__ bFh,
    unsigned short* __restrict__ WA, unsigned short* __restrict__ Wall,
    float* __restrict__ biasP)
{
  int idx = blockIdx.x*256 + threadIdx.x;      // < 656384
  if (idx >= 655360){
    int j = idx - 655360;                      // 0..1023
    int mat = j >> 8, jj = j & 255;
    const float* bp = (mat == 0) ? bFc : (mat == 1) ? bGc : (mat == 2) ? bZ : bFh;
    biasP[j] = bp[jj];
    return;
  }
  int m = idx >> 17;                           // 131072 = 2^17
  int i = idx & 131071;
  float v;
  if      (m == 0) v = wA[i];
  else if (m == 1) v = wFc[i];
  else if (m == 2) v = wGc[i];
  else if (m == 3) v = wZ[i];
  else             v = wFh[i];
  unsigned short o = f2b(v);

  int n   = (m == 0) ? (i >> 9) : ((m - 1)*256 + (i >> 9));
  int col = i & 511;
  int y  = n >> 7, nn = n & 127;
  int cb = nn >> 4, lr = nn & 15;
  int kb = col >> 6, c6 = col & 63;
  int ch = c6 >> 3, e = c6 & 7;
  int ks = ch >> 2, lq = ch & 3;
  int lane = lq*16 + lr;
  size_t pidx = ((((size_t)(y*8 + kb)*2 + ks)*8 + cb)*64 + lane)*8 + e;
  if (m == 0) WA[pidx] = o;
  else        Wall[pidx] = o;
}

// u (B,N,512) fp32 -> cB[r*256+q] bf16 (c part), hT[r*256+q] bf16 (h part), r=n*B+b
__global__ __launch_bounds__(256) void convert_u(
    const float* __restrict__ u, unsigned short* __restrict__ cB,
    unsigned short* __restrict__ hT)
{
  int r = blockIdx.x*4 + (threadIdx.x >> 6);
  int l = threadIdx.x & 63;
  int n = r >> 3, b = r & 7;
  const float* up = u + (size_t)(b*N_ + n)*512 + l*4;
  float4 cf = *(const float4*)up;
  float4 hf = *(const float4*)(up + 256);
  u16x4v c4, h4;
  c4.x = f2b(cf.x); c4.y = f2b(cf.y); c4.z = f2b(cf.z); c4.w = f2b(cf.w);
  h4.x = f2b(hf.x); h4.y = f2b(hf.y); h4.z = f2b(hf.z); h4.w = f2b(hf.w);
  *(u16x4v*)(cB + (size_t)r*256 + l*4) = c4;
  *(u16x4v*)(hT + (size_t)r*256 + l*4) = h4;
}

// ---------------- CSR build ----------------

__global__ __launch_bounds__(256) void hist_kernel(const int* __restrict__ dst, int* __restrict__ deg){
  int e = blockIdx.x*256 + threadIdx.x;   // exactly E_
  atomicAdd(&deg[dst[e]], 1);
}

__global__ __launch_bounds__(256) void scan_kernel(
    const int* __restrict__ deg, int* __restrict__ row_start, float* __restrict__ inv_deg)
{
  __shared__ int sums[256];
  int t = threadIdx.x;
  int base = t*20;
  int cnt[20];
  int local = 0;
#pragma unroll
  for (int i = 0; i < 20; ++i){
    int n = base + i;
    int d = (n < N_) ? deg[n] : 0;
    cnt[i] = d; local += d;
  }
  sums[t] = local; __syncthreads();
  for (int s = 1; s < 256; s <<= 1){
    int v = (t >= s) ? sums[t - s] : 0;
    __syncthreads();
    sums[t] += v;
    __syncthreads();
  }
  int prefix = (t == 0) ? 0 : sums[t-1];
#pragma unroll
  for (int i = 0; i < 20; ++i){
    int n = base + i;
    if (n < N_){
      row_start[n] = prefix;
      int d = cnt[i];
      inv_deg[n] = 1.0f / (float)((d > 1) ? d : 1);
      prefix += d;
    }
  }
  if (t == 255) row_start[N_] = prefix;
}

__global__ __launch_bounds__(256) void fill_kernel(
    const int* __restrict__ src, const int* __restrict__ dst,
    const int* __restrict__ row_start, int* __restrict__ cursor, int* __restrict__ csr)
{
  int e = blockIdx.x*256 + threadIdx.x;
  int d = dst[e];
  int p = atomicAdd(&cursor[d], 1);
  csr[row_start[d] + p] = src[e];
}

// one BLOCK per node n: 256 threads cover 8 batches x 32 col-segments.
__global__ __launch_bounds__(256) void gather_n_kernel(
    const unsigned short* __restrict__ hT, const int* __restrict__ csr,
    const int* __restrict__ row_start, const float* __restrict__ inv_deg,
    unsigned short* __restrict__ aggT)
{
  const int n = blockIdx.x;
  const int tid = threadIdx.x;
  const int boff = (tid >> 5)*256 + (tid & 31)*8;   // b*256 + cs*8 (shorts)
  const int e0 = row_start[n], e1 = row_start[n+1];

  float acc[8] = {};
  int e = e0;
  for (; e + 1 < e1; e += 2){
    int s0 = csr[e], s1 = csr[e+1];
    u16x8v v0 = *(const u16x8v*)(hT + (size_t)s0*2048 + boff);
    u16x8v v1 = *(const u16x8v*)(hT + (size_t)s1*2048 + boff);
#pragma unroll
    for (int i = 0; i < 8; ++i) acc[i] += b2f(v0[i]) + b2f(v1[i]);
  }
  if (e < e1){
    int s0 = csr[e];
    u16x8v v0 = *(const u16x8v*)(hT + (size_t)s0*2048 + boff);
#pragma unroll
    for (int i = 0; i < 8; ++i) acc[i] += b2f(v0[i]);
  }
  const float inv = inv_deg[n];
  u16x8v o;
#pragma unroll
  for (int i = 0; i < 8; ++i) o[i] = f2b(acc[i]*inv);
  *(u16x8v*)(aggT + (size_t)n*2048 + boff) = o;
}

// ---------------- tiled GEMM (A via LDS dbuf, B direct-from-L2, counted vmcnt) ----
// C[m, n] = act( [A0|A1](m, 0:512) . Bw(n, 0:512) + bias[n] )
// 128x128 tile, 4 waves (2x2 of 64x64), BK=64.
// A: double-buffered global_load_lds (16 KB/step) with XOR-chunk swizzle on the
//    GLOBAL address; fragment ds_read_b128 bank-conflict-free. LDS = 34816 B.
// B: L2-resident (<=1 MB), loaded DIRECTLY into registers from the fragment-
//    packed layout (8 x 1KB coalesced wave loads per K-step), prefetched one
//    K-step ahead into ping-pong register arrays. No LDS, no barrier dep.
// Sync per K-step: issue 4 A-stages, fence, issue 8 B-prefetches, compute,
//    s_waitcnt vmcnt(8)  <- waits ONLY the 4 oldest (A-stages); the 8 B loads
//    stay in flight across the barrier (T4). sched_barrier(0) pins ds_reads
//    below the barrier (rule #18).
// 1-D grid id decode groups the NY col-slab blocks of one row-tile x into a
// 64-id window with id % 8 == const -> same XCD -> A row-tile is L2-served.
// MODE 0 (NY=2): gemm1 -> dst[r*256 + col], softplus.
// MODE 1 (NY=8): gemm_big -> act[(b*N+n)*1024 + col], tanh on slab y>>1==2.

__device__ __forceinline__ void stage_a(
    const unsigned short* __restrict__ As, int m0, int ak,
    int srow, int schunk, int w, unsigned short* lbuf)
{
#pragma unroll
  for (int i = 0; i < 4; ++i){
    const unsigned short* gp = As + (size_t)(m0 + i*32 + srow)*256 + ak + schunk*8;
    unsigned short* lp = lbuf + (i*32 + w*8)*64;
    __builtin_amdgcn_global_load_lds((const __attribute__((address_space(1))) void*)gp,
                                     (__attribute__((address_space(3))) void*)lp, 16, 0, 0);
  }
}

__device__ __forceinline__ void load_b(
    const unsigned short* __restrict__ Bp, int y, int kb, int wc, int l, v8bf (&b)[8])
{
#pragma unroll
  for (int ks = 0; ks < 2; ++ks)
#pragma unroll
    for (int ct = 0; ct < 4; ++ct)
      b[ks*4+ct] = *(const v8bf*)(Bp +
          ((((size_t)(y*8 + kb)*2 + ks)*8 + wc*4 + ct)*64 + l)*8);
}

__device__ __forceinline__ void compute_tile(
    const unsigned short* lA, int wr, int lq, int lr,
    const v8bf (&bb)[8], v4f (&acc)[4][4])
{
#pragma unroll
  for (int ks = 0; ks < 2; ++ks){
    v8bf a[4];
#pragma unroll
    for (int rt = 0; rt < 4; ++rt){
      const int ar = wr*64 + rt*16 + lr;
      a[rt] = *(const v8bf*)(lA + ar*64 + (((ks*4 + lq) ^ (ar & 7)))*8);
    }
#pragma unroll
    for (int rt = 0; rt < 4; ++rt)
#pragma unroll
      for (int ct = 0; ct < 4; ++ct)
        acc[rt][ct] = __builtin_amdgcn_mfma_f32_16x16x32_bf16(a[rt], bb[ks*4+ct], acc[rt][ct], 0, 0, 0);
  }
}

template<int MODE>
__global__ __launch_bounds__(256, 3) void gemm_tiled(
    const unsigned short* __restrict__ A0, const unsigned short* __restrict__ A1,
    const unsigned short* __restrict__ Bp, const float* __restrict__ bias,
    unsigned short* dstp)
{
  const int id = blockIdx.x;
  int x, y;
  if (MODE == 1){
    const int u6 = id & 63;
    y = u6 >> 3;
    x = (id >> 6)*8 + (u6 & 7);
  } else {
    const int u4 = id & 15;
    y = u4 >> 3;
    x = (id >> 4)*8 + (u4 & 7);
  }
  if (x >= XT_) return;

  // A staging dbuf: 2 x (128x64) bf16 = 32 KB; epilogue repack 128x136 = 34816 B.
  __shared__ unsigned short lds[17408];

  const int tid = threadIdx.x;
  const int w  = tid >> 6, l = tid & 63;
  const int wr = w >> 1,  wc = w & 1;
  const int lq = l >> 4,  lr = l & 15;
  const int m0 = x * 128;
  const int n0 = y * 128;

  // staging: per issue of 32 rows, thread covers row (tid>>3),
  // fetching global 16B chunk ((tid&7) ^ (row&7)) into LDS slot (tid&7).
  const int srow   = tid >> 3;                 // 0..31
  const int schunk = (tid & 7) ^ (srow & 7);   // swizzled k-chunk

  v4f acc[4][4] = {};
  v8bf b0[8], b1[8];

  // prologue: stage A(0) -> buf0 (issued FIRST = oldest 4 vmem), prefetch B(0).
  stage_a(A0, m0, 0, srow, schunk, w, lds);
  asm volatile("" ::: "memory");               // keep B loads after the stages
  load_b(Bp, y, 0, wc, l, b0);
  asm volatile("s_waitcnt vmcnt(8)" ::: "memory");  // A(0) landed; B(0) may fly
  __builtin_amdgcn_s_barrier();
  __builtin_amdgcn_sched_barrier(0);

#pragma unroll
  for (int kb = 0; kb < 7; ++kb){
    const int kn = kb + 1;
    stage_a((kn < 4) ? A0 : A1, m0, (kn & 3)*64, srow, schunk, w,
            lds + (kn & 1)*8192);
    asm volatile("" ::: "memory");             // keep B loads after the stages
    if (kn & 1) load_b(Bp, y, kn, wc, l, b1);
    else        load_b(Bp, y, kn, wc, l, b0);
    if (kb & 1) compute_tile(lds + 8192, wr, lq, lr, b1, acc);
    else        compute_tile(lds,        wr, lq, lr, b0, acc);
    // wait only the 4 A-stage loads (oldest); 8 B prefetches cross the barrier
    asm volatile("s_waitcnt vmcnt(8)" ::: "memory");
    __builtin_amdgcn_s_barrier();
    __builtin_amdgcn_sched_barrier(0);
  }
  compute_tile(lds + 8192, wr, lq, lr, b1, acc);   // kb=7: buf1, b1

  float bv[4];
#pragma unroll
  for (int ct = 0; ct < 4; ++ct) bv[ct] = bias[n0 + wc*64 + ct*16 + lr];

  const bool is_tanh = (MODE == 1) && ((y >> 1) == 2);

  __syncthreads();   // done reading lds; reuse as output repack buffer
#pragma unroll
  for (int rt = 0; rt < 4; ++rt){
#pragma unroll
    for (int ct = 0; ct < 4; ++ct){
      const int col = wc*64 + ct*16 + lr;
#pragma unroll
      for (int reg = 0; reg < 4; ++reg){
        const int row = wr*64 + rt*16 + lq*4 + reg;
        const float xv = acc[rt][ct][reg] + bv[ct];
        const float v = is_tanh ? tanh_(xv) : softplus_(xv);
        lds[row*136 + col] = f2b(v);
      }
    }
  }
  __syncthreads();

  // coalesced store: 8 issues, each row gets 16 lanes x 16B = 256B contiguous
#pragma unroll
  for (int i = 0; i < 8; ++i){
    const int row = i*16 + (tid >> 4);
    const int r = m0 + row;
    if (r < M_){
      const uint4 v = *(const uint4*)(lds + row*136 + (tid & 15)*8);
      if (MODE == 0){
        *(uint4*)(dstp + (size_t)r*256 + n0 + (tid & 15)*8) = v;
      } else {
        const int n = r >> 3, b = r & 7;
        *(uint4*)(dstp + ((size_t)b*N_ + n)*1024 + n0 + (tid & 15)*8) = v;
      }
    }
  }
}

// ---------------- epilogue: dc with projection + dh ----------------

__global__ __launch_bounds__(256) void epilogue_kernel(
    const unsigned short* act, const float* __restrict__ u, float* out)
{
  int r = blockIdx.x*4 + (threadIdx.x >> 6);
  int l = threadIdx.x & 63;
  int n = r >> 3, b = r & 7;
  const size_t rr = (size_t)(b*N_ + n);
  const unsigned short* arow = act + rr*1024;
  const float* urow = u + rr*512;
  float* orow = out + rr*512;

  u16x4v fc4 = *(const u16x4v*)(arow +        l*4);
  u16x4v gc4 = *(const u16x4v*)(arow + 256 +  l*4);
  u16x4v z4  = *(const u16x4v*)(arow + 512 +  l*4);
  u16x4v fh4 = *(const u16x4v*)(arow + 768 +  l*4);
  float4 c4f = *(const float4*)(urow + l*4);
  float4 h4f = *(const float4*)(urow + 256 + l*4);

  float c[4] = {c4f.x, c4f.y, c4f.z, c4f.w};
  float h[4] = {h4f.x, h4f.y, h4f.z, h4f.w};
  float dc[4], fh[4];
  float num = 0.f, den = 0.f;
#pragma unroll
  for (int i = 0; i < 4; ++i){
    float fc = b2f(fc4[i]), gc = b2f(gc4[i]), z = b2f(z4[i]);
    fh[i] = b2f(fh4[i]);
    dc[i] = -fc*c[i] + gc*z;
    num += dc[i]*c[i];
    den += c[i]*c[i];
  }
#pragma unroll
  for (int s = 1; s < 64; s <<= 1){
    num += __shfl_xor(num, s, 64);
    den += __shfl_xor(den, s, 64);
  }
  const float proj = num / den;

  float4 o, oh;
  o.x = dc[0] - proj*c[0]; o.y = dc[1] - proj*c[1];
  o.z = dc[2] - proj*c[2]; o.w = dc[3] - proj*c[3];
  oh.x = -fh[0]*h[0]; oh.y = -fh[1]*h[1];
  oh.z = -fh[2]*h[2]; oh.w = -fh[3]*h[3];
  *(float4*)(orow + l*4) = o;
  *(float4*)(orow + 256 + l*4) = oh;
}

// ---------------- launch ----------------

extern "C" void kernel_launch(void* const* d_in, const int* in_sizes, int n_in,
                              void* d_out, int out_size, void* d_ws, size_t ws_size,
                              hipStream_t stream) {
  const float* u    = (const float*)d_in[0];
  const int*   src  = (const int*)d_in[1];
  const int*   dst  = (const int*)d_in[2];
  const float* wFc  = (const float*)d_in[4];
  const float* bFc  = (const float*)d_in[5];
  const float* wFh  = (const float*)d_in[6];
  const float* bFh  = (const float*)d_in[7];
  const float* wGc  = (const float*)d_in[8];
  const float* bGc  = (const float*)d_in[9];
  const float* wZ   = (const float*)d_in[10];
  const float* bZ   = (const float*)d_in[11];
  const float* wA   = (const float*)d_in[12];
  const float* bA   = (const float*)d_in[13];
  float* out = (float*)d_out;
  unsigned short* act = (unsigned short*)d_out;   // bf16 activations overlay out

  // ws layout. GEMM A-staging over-reads up to 64 rows past the end of
  // hT/cB/aggT/hB — each overflow lands in the NEXT allocation (readable garbage,
  // results discarded by the r < M_ store guard). Keep this buffer order.
  char* W = (char*)d_ws;
  unsigned short* hT   = (unsigned short*)(W + 0);           // 20,480,000 B
  unsigned short* cB   = (unsigned short*)(W + 20480000);
  unsigned short* aggT = (unsigned short*)(W + 40960000);
  unsigned short* hB   = (unsigned short*)(W + 61440000);
  unsigned short* WA   = (unsigned short*)(W + 81920000);    // 262,144 B (packed)
  unsigned short* Wall = (unsigned short*)(W + 82182144);    // 1,048,576 B (packed)
  float* biasP   = (float*)(W + 83230720);                   // 4,096 B
  int* deg       = (int*)(W + 83234816);
  int* row_start = (int*)(W + 83255296);
  int* cursor    = (int*)(W + 83275776);
  int* csr       = (int*)(W + 83296256);                     // 640,000 B
  float* inv_deg = (float*)(W + 83936256);

  zero_int2<<<(N_ + 255)/256, 256, 0, stream>>>(deg, cursor, N_);
  convert_weights<<<2564, 256, 0, stream>>>(wA, wFc, wGc, wZ, wFh,
                                            bFc, bGc, bZ, bFh, WA, Wall, biasP);
  convert_u<<<M_/4, 256, 0, stream>>>(u, cB, hT);
  hist_kernel<<<E_/256, 256, 0, stream>>>(dst, deg);
  scan_kernel<<<1, 256, 0, stream>>>(deg, row_start, inv_deg);
  fill_kernel<<<E_/256, 256, 0, stream>>>(src, dst, row_start, cursor, csr);
  gather_n_kernel<<<N_, 256, 0, stream>>>(hT, csr, row_start, inv_deg, aggT);

  // 1-D swizzled grids: 40 g-groups of 8 x-tiles (x<313 guard inside)
  gemm_tiled<0><<<40*16, 256, 0, stream>>>(hT, aggT, WA, bA, hB);
  gemm_tiled<1><<<40*64, 256, 0, stream>>>(cB, hB, Wall, biasP, act);

  epilogue_kernel<<<M_/4, 256, 0, stream>>>(act, u, out);
}

// Round 3
// 397.822 us; speedup vs baseline: 1.0652x; 1.0062x over previous
//
#include <hip/hip_runtime.h>
#include <math.h>

// Problem constants
#define B_ 8
#define N_ 5000
#define E_ 160000
#define M_ 40000      // N_*B_ rows, r = n*B_ + b
#define K_ 512
#define XT_ 313       // (M_+127)/128 row tiles

typedef __bf16 v8bf __attribute__((ext_vector_type(8)));
typedef float  v4f  __attribute__((ext_vector_type(4)));
typedef unsigned short u16x4v __attribute__((ext_vector_type(4)));
typedef unsigned short u16x8v __attribute__((ext_vector_type(8)));

__device__ __forceinline__ unsigned short f2b(float f){
  unsigned int u = __builtin_bit_cast(unsigned int, f);
  u += 0x7FFFu + ((u >> 16) & 1u);          // round-to-nearest-even
  return (unsigned short)(u >> 16);
}
__device__ __forceinline__ float b2f(unsigned short s){
  return __builtin_bit_cast(float, ((unsigned int)s) << 16);
}
__device__ __forceinline__ float softplus_(float x){
  // HW v_exp/v_log; x>15 -> x (exp overflow guard); bf16 output absorbs ~1e-6 err
  return (x > 15.0f) ? x : __logf(1.0f + __expf(x));
}
__device__ __forceinline__ float tanh_(float x){
  float e = __expf(2.0f*x);
  return 1.0f - 2.0f/(e + 1.0f);
}

// ---------------- setup kernels ----------------

__global__ __launch_bounds__(256) void zero_int2(int* a, int* b, int n){
  int i = blockIdx.x*256 + threadIdx.x;
  if (i < n){ a[i] = 0; b[i] = 0; }
}

// 5 * 131072 weight elems + 1024 packed bias. m: 0->WA, 1..4->Wall rows [Fc;Gc;Z;Fh]
// B matrices are written in a REGISTER-FRAGMENT-PACKED layout so the GEMM can
// load its MFMA B-fragments directly from L2 with perfectly coalesced 1 KB
// wave loads (no LDS round-trip for B):
//   pidx(n,col): y=n>>7, nn=n&127, cb=nn>>4, lr=nn&15,
//                kb=col>>6, ch=(col&63)>>3, e=col&7, ks=ch>>2, lq=ch&3,
//                lane=lq*16+lr
//   pidx = ((((y*8+kb)*2+ks)*8+cb)*64+lane)*8+e
// In the GEMM, wave (wc), fragment (ks,ct), lane l reads
//   Bp[((((y*8+kb)*2+ks)*8+wc*4+ct)*64+l)*8 .. +7]
// which equals Bw[n0 + wc*64+ct*16+(l&15)][kb*64+(ks*4+(l>>4))*8 + 0..7].
__global__ __launch_bounds__(256) void convert_weights(
    const float* __restrict__ wA, const float* __restrict__ wFc,
    const float* __restrict__ wGc, const float* __restrict__ wZ,
    const float* __restrict__ wFh,
    const float* __restrict__ bFc, const float* __restrict__ bGc,
    const float* __restrict__ bZ,  const float* __restrict__ bFh,
    unsigned short* __restrict__ WA, unsigned short* __restrict__ Wall,
    float* __restrict__ biasP)
{
  int idx = blockIdx.x*256 + threadIdx.x;      // < 656384
  if (idx >= 655360){
    int j = idx - 655360;                      // 0..1023
    int mat = j >> 8, jj = j & 255;
    const float* bp = (mat == 0) ? bFc : (mat == 1) ? bGc : (mat == 2) ? bZ : bFh;
    biasP[j] = bp[jj];
    return;
  }
  int m = idx >> 17;                           // 131072 = 2^17
  int i = idx & 131071;
  float v;
  if      (m == 0) v = wA[i];
  else if (m == 1) v = wFc[i];
  else if (m == 2) v = wGc[i];
  else if (m == 3) v = wZ[i];
  else             v = wFh[i];
  unsigned short o = f2b(v);

  int n   = (m == 0) ? (i >> 9) : ((m - 1)*256 + (i >> 9));
  int col = i & 511;
  int y  = n >> 7, nn = n & 127;
  int cb = nn >> 4, lr = nn & 15;
  int kb = col >> 6, c6 = col & 63;
  int ch = c6 >> 3, e = c6 & 7;
  int ks = ch >> 2, lq = ch & 3;
  int lane = lq*16 + lr;
  size_t pidx = ((((size_t)(y*8 + kb)*2 + ks)*8 + cb)*64 + lane)*8 + e;
  if (m == 0) WA[pidx] = o;
  else        Wall[pidx] = o;
}

// u (B,N,512) fp32 -> cB[r*256+q] bf16 (c part), hT[r*256+q] bf16 (h part), r=n*B+b
__global__ __launch_bounds__(256) void convert_u(
    const float* __restrict__ u, unsigned short* __restrict__ cB,
    unsigned short* __restrict__ hT)
{
  int r = blockIdx.x*4 + (threadIdx.x >> 6);
  int l = threadIdx.x & 63;
  int n = r >> 3, b = r & 7;
  const float* up = u + (size_t)(b*N_ + n)*512 + l*4;
  float4 cf = *(const float4*)up;
  float4 hf = *(const float4*)(up + 256);
  u16x4v c4, h4;
  c4.x = f2b(cf.x); c4.y = f2b(cf.y); c4.z = f2b(cf.z); c4.w = f2b(cf.w);
  h4.x = f2b(hf.x); h4.y = f2b(hf.y); h4.z = f2b(hf.z); h4.w = f2b(hf.w);
  *(u16x4v*)(cB + (size_t)r*256 + l*4) = c4;
  *(u16x4v*)(hT + (size_t)r*256 + l*4) = h4;
}

// ---------------- CSR build ----------------

__global__ __launch_bounds__(256) void hist_kernel(const int* __restrict__ dst, int* __restrict__ deg){
  int e = blockIdx.x*256 + threadIdx.x;   // exactly E_
  atomicAdd(&deg[dst[e]], 1);
}

__global__ __launch_bounds__(256) void scan_kernel(
    const int* __restrict__ deg, int* __restrict__ row_start, float* __restrict__ inv_deg)
{
  __shared__ int sums[256];
  int t = threadIdx.x;
  int base = t*20;
  int cnt[20];
  int local = 0;
#pragma unroll
  for (int i = 0; i < 20; ++i){
    int n = base + i;
    int d = (n < N_) ? deg[n] : 0;
    cnt[i] = d; local += d;
  }
  sums[t] = local; __syncthreads();
  for (int s = 1; s < 256; s <<= 1){
    int v = (t >= s) ? sums[t - s] : 0;
    __syncthreads();
    sums[t] += v;
    __syncthreads();
  }
  int prefix = (t == 0) ? 0 : sums[t-1];
#pragma unroll
  for (int i = 0; i < 20; ++i){
    int n = base + i;
    if (n < N_){
      row_start[n] = prefix;
      int d = cnt[i];
      inv_deg[n] = 1.0f / (float)((d > 1) ? d : 1);
      prefix += d;
    }
  }
  if (t == 255) row_start[N_] = prefix;
}

__global__ __launch_bounds__(256) void fill_kernel(
    const int* __restrict__ src, const int* __restrict__ dst,
    const int* __restrict__ row_start, int* __restrict__ cursor, int* __restrict__ csr)
{
  int e = blockIdx.x*256 + threadIdx.x;
  int d = dst[e];
  int p = atomicAdd(&cursor[d], 1);
  csr[row_start[d] + p] = src[e];
}

// one BLOCK per node n: 256 threads cover 8 batches x 32 col-segments.
// Latency fix (T14-shape): the csr segment is staged to LDS FIRST (removes the
// csr->row dependent-load chain), then row loads are issued 8-deep per wave
// (independent 1 KB wave loads -> MLP 8 vs the old 2, which was gated on the
// uniform csr load each iteration).
__global__ __launch_bounds__(256) void gather_n_kernel(
    const unsigned short* __restrict__ hT, const int* __restrict__ csr,
    const int* __restrict__ row_start, const float* __restrict__ inv_deg,
    unsigned short* __restrict__ aggT)
{
  const int n = blockIdx.x;
  const int tid = threadIdx.x;
  const int boff = (tid >> 5)*256 + (tid & 31)*8;   // b*256 + cs*8 (shorts)
  const int e0 = row_start[n], e1 = row_start[n+1];

  __shared__ int sidx[256];
  float acc[8] = {};

  for (int base = e0; base < e1; base += 256){
    const int cnt = min(256, e1 - base);
    if (tid < cnt) sidx[tid] = csr[base + tid];
    __syncthreads();

    int e = 0;
    for (; e + 7 < cnt; e += 8){
      u16x8v v[8];
#pragma unroll
      for (int j = 0; j < 8; ++j){
        const int s = sidx[e + j];
        v[j] = *(const u16x8v*)(hT + (size_t)s*2048 + boff);
      }
#pragma unroll
      for (int j = 0; j < 8; ++j)
#pragma unroll
        for (int i = 0; i < 8; ++i) acc[i] += b2f(v[j][i]);
    }
    for (; e + 1 < cnt; e += 2){
      const int s0 = sidx[e], s1 = sidx[e+1];
      u16x8v v0 = *(const u16x8v*)(hT + (size_t)s0*2048 + boff);
      u16x8v v1 = *(const u16x8v*)(hT + (size_t)s1*2048 + boff);
#pragma unroll
      for (int i = 0; i < 8; ++i) acc[i] += b2f(v0[i]) + b2f(v1[i]);
    }
    if (e < cnt){
      const int s0 = sidx[e];
      u16x8v v0 = *(const u16x8v*)(hT + (size_t)s0*2048 + boff);
#pragma unroll
      for (int i = 0; i < 8; ++i) acc[i] += b2f(v0[i]);
    }
    __syncthreads();   // safe sidx overwrite if deg > 256 (rare)
  }

  const float inv = inv_deg[n];
  u16x8v o;
#pragma unroll
  for (int i = 0; i < 8; ++i) o[i] = f2b(acc[i]*inv);
  *(u16x8v*)(aggT + (size_t)n*2048 + boff) = o;
}

// ---------------- tiled GEMM (A via LDS dbuf, B direct-from-L2, counted vmcnt) ----
// C[m, n] = act( [A0|A1](m, 0:512) . Bw(n, 0:512) + bias[n] )
// 128x128 tile, 4 waves (2x2 of 64x64), BK=64.
// A: double-buffered global_load_lds (16 KB/step) with XOR-chunk swizzle on the
//    GLOBAL address; fragment ds_read_b128 bank-conflict-free. LDS = 34816 B.
// B: L2-resident (<=1 MB), loaded DIRECTLY into registers from the fragment-
//    packed layout (8 x 1KB coalesced wave loads per K-step), prefetched one
//    K-step ahead into ping-pong register arrays. No LDS, no barrier dep.
// Sync per K-step: issue 4 A-stages, fence, issue 8 B-prefetches, compute,
//    s_waitcnt vmcnt(8)  <- waits ONLY the 4 oldest (A-stages); the 8 B loads
//    stay in flight across the barrier (T4). sched_barrier(0) pins ds_reads
//    below the barrier (rule #18).
// MODE 0 (NY=2): gemm1 -> dst[r*256 + col], softplus.
// MODE 1 (NY=8): gemm_big -> act[(b*N+n)*1024 + col], tanh on slab y>>1==2.

__device__ __forceinline__ void stage_a(
    const unsigned short* __restrict__ As, int m0, int ak,
    int srow, int schunk, int w, unsigned short* lbuf)
{
#pragma unroll
  for (int i = 0; i < 4; ++i){
    const unsigned short* gp = As + (size_t)(m0 + i*32 + srow)*256 + ak + schunk*8;
    unsigned short* lp = lbuf + (i*32 + w*8)*64;
    __builtin_amdgcn_global_load_lds((const __attribute__((address_space(1))) void*)gp,
                                     (__attribute__((address_space(3))) void*)lp, 16, 0, 0);
  }
}

__device__ __forceinline__ void load_b(
    const unsigned short* __restrict__ Bp, int y, int kb, int wc, int l, v8bf (&b)[8])
{
#pragma unroll
  for (int ks = 0; ks < 2; ++ks)
#pragma unroll
    for (int ct = 0; ct < 4; ++ct)
      b[ks*4+ct] = *(const v8bf*)(Bp +
          ((((size_t)(y*8 + kb)*2 + ks)*8 + wc*4 + ct)*64 + l)*8);
}

__device__ __forceinline__ void compute_tile(
    const unsigned short* lA, int wr, int lq, int lr,
    const v8bf (&bb)[8], v4f (&acc)[4][4])
{
#pragma unroll
  for (int ks = 0; ks < 2; ++ks){
    v8bf a[4];
#pragma unroll
    for (int rt = 0; rt < 4; ++rt){
      const int ar = wr*64 + rt*16 + lr;
      a[rt] = *(const v8bf*)(lA + ar*64 + (((ks*4 + lq) ^ (ar & 7)))*8);
    }
#pragma unroll
    for (int rt = 0; rt < 4; ++rt)
#pragma unroll
      for (int ct = 0; ct < 4; ++ct)
        acc[rt][ct] = __builtin_amdgcn_mfma_f32_16x16x32_bf16(a[rt], bb[ks*4+ct], acc[rt][ct], 0, 0, 0);
  }
}

template<int MODE>
__global__ __launch_bounds__(256, 3) void gemm_tiled(
    const unsigned short* __restrict__ A0, const unsigned short* __restrict__ A1,
    const unsigned short* __restrict__ Bp, const float* __restrict__ bias,
    unsigned short* dstp)
{
  const int id = blockIdx.x;
  int x, y;
  if (MODE == 1){
    const int u6 = id & 63;
    y = u6 >> 3;
    x = (id >> 6)*8 + (u6 & 7);
  } else {
    const int u4 = id & 15;
    y = u4 >> 3;
    x = (id >> 4)*8 + (u4 & 7);
  }
  if (x >= XT_) return;

  // A staging dbuf: 2 x (128x64) bf16 = 32 KB; epilogue repack 128x136 = 34816 B.
  __shared__ unsigned short lds[17408];

  const int tid = threadIdx.x;
  const int w  = tid >> 6, l = tid & 63;
  const int wr = w >> 1,  wc = w & 1;
  const int lq = l >> 4,  lr = l & 15;
  const int m0 = x * 128;
  const int n0 = y * 128;

  // staging: per issue of 32 rows, thread covers row (tid>>3),
  // fetching global 16B chunk ((tid&7) ^ (row&7)) into LDS slot (tid&7).
  const int srow   = tid >> 3;                 // 0..31
  const int schunk = (tid & 7) ^ (srow & 7);   // swizzled k-chunk

  v4f acc[4][4] = {};
  v8bf b0[8], b1[8];

  // prologue: stage A(0) -> buf0 (issued FIRST = oldest 4 vmem), prefetch B(0).
  stage_a(A0, m0, 0, srow, schunk, w, lds);
  asm volatile("" ::: "memory");               // keep B loads after the stages
  load_b(Bp, y, 0, wc, l, b0);
  asm volatile("s_waitcnt vmcnt(8)" ::: "memory");  // A(0) landed; B(0) may fly
  __builtin_amdgcn_s_barrier();
  __builtin_amdgcn_sched_barrier(0);

#pragma unroll
  for (int kb = 0; kb < 7; ++kb){
    const int kn = kb + 1;
    stage_a((kn < 4) ? A0 : A1, m0, (kn & 3)*64, srow, schunk, w,
            lds + (kn & 1)*8192);
    asm volatile("" ::: "memory");             // keep B loads after the stages
    if (kn & 1) load_b(Bp, y, kn, wc, l, b1);
    else        load_b(Bp, y, kn, wc, l, b0);
    if (kb & 1) compute_tile(lds + 8192, wr, lq, lr, b1, acc);
    else        compute_tile(lds,        wr, lq, lr, b0, acc);
    // wait only the 4 A-stage loads (oldest); 8 B prefetches cross the barrier
    asm volatile("s_waitcnt vmcnt(8)" ::: "memory");
    __builtin_amdgcn_s_barrier();
    __builtin_amdgcn_sched_barrier(0);
  }
  compute_tile(lds + 8192, wr, lq, lr, b1, acc);   // kb=7: buf1, b1

  float bv[4];
#pragma unroll
  for (int ct = 0; ct < 4; ++ct) bv[ct] = bias[n0 + wc*64 + ct*16 + lr];

  const bool is_tanh = (MODE == 1) && ((y >> 1) == 2);

  __syncthreads();   // done reading lds; reuse as output repack buffer
#pragma unroll
  for (int rt = 0; rt < 4; ++rt){
#pragma unroll
    for (int ct = 0; ct < 4; ++ct){
      const int col = wc*64 + ct*16 + lr;
#pragma unroll
      for (int reg = 0; reg < 4; ++reg){
        const int row = wr*64 + rt*16 + lq*4 + reg;
        const float xv = acc[rt][ct][reg] + bv[ct];
        const float v = is_tanh ? tanh_(xv) : softplus_(xv);
        lds[row*136 + col] = f2b(v);
      }
    }
  }
  __syncthreads();

  // coalesced store: 8 issues, each row gets 16 lanes x 16B = 256B contiguous
#pragma unroll
  for (int i = 0; i < 8; ++i){
    const int row = i*16 + (tid >> 4);
    const int r = m0 + row;
    if (r < M_){
      const uint4 v = *(const uint4*)(lds + row*136 + (tid & 15)*8);
      if (MODE == 0){
        *(uint4*)(dstp + (size_t)r*256 + n0 + (tid & 15)*8) = v;
      } else {
        const int n = r >> 3, b = r & 7;
        *(uint4*)(dstp + ((size_t)b*N_ + n)*1024 + n0 + (tid & 15)*8) = v;
      }
    }
  }
}

// ---------------- epilogue: dc with projection + dh ----------------

__global__ __launch_bounds__(256) void epilogue_kernel(
    const unsigned short* act, const float* __restrict__ u, float* out)
{
  int r = blockIdx.x*4 + (threadIdx.x >> 6);
  int l = threadIdx.x & 63;
  int n = r >> 3, b = r & 7;
  const size_t rr = (size_t)(b*N_ + n);
  const unsigned short* arow = act + rr*1024;
  const float* urow = u + rr*512;
  float* orow = out + rr*512;

  u16x4v fc4 = *(const u16x4v*)(arow +        l*4);
  u16x4v gc4 = *(const u16x4v*)(arow + 256 +  l*4);
  u16x4v z4  = *(const u16x4v*)(arow + 512 +  l*4);
  u16x4v fh4 = *(const u16x4v*)(arow + 768 +  l*4);
  float4 c4f = *(const float4*)(urow + l*4);
  float4 h4f = *(const float4*)(urow + 256 + l*4);

  float c[4] = {c4f.x, c4f.y, c4f.z, c4f.w};
  float h[4] = {h4f.x, h4f.y, h4f.z, h4f.w};
  float dc[4], fh[4];
  float num = 0.f, den = 0.f;
#pragma unroll
  for (int i = 0; i < 4; ++i){
    float fc = b2f(fc4[i]), gc = b2f(gc4[i]), z = b2f(z4[i]);
    fh[i] = b2f(fh4[i]);
    dc[i] = -fc*c[i] + gc*z;
    num += dc[i]*c[i];
    den += c[i]*c[i];
  }
#pragma unroll
  for (int s = 1; s < 64; s <<= 1){
    num += __shfl_xor(num, s, 64);
    den += __shfl_xor(den, s, 64);
  }
  const float proj = num / den;

  float4 o, oh;
  o.x = dc[0] - proj*c[0]; o.y = dc[1] - proj*c[1];
  o.z = dc[2] - proj*c[2]; o.w = dc[3] - proj*c[3];
  oh.x = -fh[0]*h[0]; oh.y = -fh[1]*h[1];
  oh.z = -fh[2]*h[2]; oh.w = -fh[3]*h[3];
  *(float4*)(orow + l*4) = o;
  *(float4*)(orow + 256 + l*4) = oh;
}

// ---------------- launch ----------------

extern "C" void kernel_launch(void* const* d_in, const int* in_sizes, int n_in,
                              void* d_out, int out_size, void* d_ws, size_t ws_size,
                              hipStream_t stream) {
  const float* u    = (const float*)d_in[0];
  const int*   src  = (const int*)d_in[1];
  const int*   dst  = (const int*)d_in[2];
  const float* wFc  = (const float*)d_in[4];
  const float* bFc  = (const float*)d_in[5];
  const float* wFh  = (const float*)d_in[6];
  const float* bFh  = (const float*)d_in[7];
  const float* wGc  = (const float*)d_in[8];
  const float* bGc  = (const float*)d_in[9];
  const float* wZ   = (const float*)d_in[10];
  const float* bZ   = (const float*)d_in[11];
  const float* wA   = (const float*)d_in[12];
  const float* bA   = (const float*)d_in[13];
  float* out = (float*)d_out;
  unsigned short* act = (unsigned short*)d_out;   // bf16 activations overlay out

  // ws layout. GEMM A-staging over-reads up to 64 rows past the end of
  // hT/cB/aggT/hB — each overflow lands in the NEXT allocation (readable garbage,
  // results discarded by the r < M_ store guard). Keep this buffer order.
  char* W = (char*)d_ws;
  unsigned short* hT   = (unsigned short*)(W + 0);           // 20,480,000 B
  unsigned short* cB   = (unsigned short*)(W + 20480000);
  unsigned short* aggT = (unsigned short*)(W + 40960000);
  unsigned short* hB   = (unsigned short*)(W + 61440000);
  unsigned short* WA   = (unsigned short*)(W + 81920000);    // 262,144 B (packed)
  unsigned short* Wall = (unsigned short*)(W + 82182144);    // 1,048,576 B (packed)
  float* biasP   = (float*)(W + 83230720);                   // 4,096 B
  int* deg       = (int*)(W + 83234816);
  int* row_start = (int*)(W + 83255296);
  int* cursor    = (int*)(W + 83275776);
  int* csr       = (int*)(W + 83296256);                     // 640,000 B
  float* inv_deg = (float*)(W + 83936256);

  zero_int2<<<(N_ + 255)/256, 256, 0, stream>>>(deg, cursor, N_);
  convert_weights<<<2564, 256, 0, stream>>>(wA, wFc, wGc, wZ, wFh,
                                            bFc, bGc, bZ, bFh, WA, Wall, biasP);
  convert_u<<<M_/4, 256, 0, stream>>>(u, cB, hT);
  hist_kernel<<<E_/256, 256, 0, stream>>>(dst, deg);
  scan_kernel<<<1, 256, 0, stream>>>(deg, row_start, inv_deg);
  fill_kernel<<<E_/256, 256, 0, stream>>>(src, dst, row_start, cursor, csr);
  gather_n_kernel<<<N_, 256, 0, stream>>>(hT, csr, row_start, inv_deg, aggT);

  // 1-D swizzled grids: 40 g-groups of 8 x-tiles (x<313 guard inside)
  gemm_tiled<0><<<40*16, 256, 0, stream>>>(hT, aggT, WA, bA, hB);
  gemm_tiled<1><<<40*64, 256, 0, stream>>>(cB, hB, Wall, biasP, act);

  epilogue_kernel<<<M_/4, 256, 0, stream>>>(act, u, out);
}

// Round 4
// 348.369 us; speedup vs baseline: 1.2164x; 1.1420x over previous
//
#include <hip/hip_runtime.h>
#include <math.h>

// Problem constants
#define B_ 8
#define N_ 5000
#define E_ 160000
#define M_ 40000      // N_*B_ rows, r = n*B_ + b
#define K_ 512
#define XT_ 313       // (M_+127)/128 row tiles

typedef __bf16 v8bf __attribute__((ext_vector_type(8)));
typedef float  v4f  __attribute__((ext_vector_type(4)));
typedef unsigned short u16x4v __attribute__((ext_vector_type(4)));
typedef unsigned short u16x8v __attribute__((ext_vector_type(8)));

__device__ __forceinline__ unsigned short f2b(float f){
  unsigned int u = __builtin_bit_cast(unsigned int, f);
  u += 0x7FFFu + ((u >> 16) & 1u);          // round-to-nearest-even
  return (unsigned short)(u >> 16);
}
__device__ __forceinline__ float b2f(unsigned short s){
  return __builtin_bit_cast(float, ((unsigned int)s) << 16);
}
__device__ __forceinline__ float softplus_(float x){
  // HW v_exp/v_log; x>15 -> x (exp overflow guard); bf16 output absorbs ~1e-6 err
  return (x > 15.0f) ? x : __logf(1.0f + __expf(x));
}
__device__ __forceinline__ float tanh_(float x){
  float e = __expf(2.0f*x);
  return 1.0f - 2.0f/(e + 1.0f);
}

// ---------------- setup kernels ----------------

__global__ __launch_bounds__(256) void zero_int2(int* a, int* b, int n){
  int i = blockIdx.x*256 + threadIdx.x;
  if (i < n){ a[i] = 0; b[i] = 0; }
}

// 5 * 131072 weight elems + 1024 packed bias. m: 0->WA, 1..4->Wall rows [Fc;Gc;Z;Fh]
// B matrices are written in a REGISTER-FRAGMENT-PACKED layout so the GEMM can
// load its MFMA B-fragments directly from L2 with perfectly coalesced 1 KB
// wave loads (no LDS round-trip for B):
//   pidx(n,col): y=n>>7, nn=n&127, cb=nn>>4, lr=nn&15,
//                kb=col>>6, ch=(col&63)>>3, e=col&7, ks=ch>>2, lq=ch&3,
//                lane=lq*16+lr
//   pidx = ((((y*8+kb)*2+ks)*8+cb)*64+lane)*8+e
// In the GEMM, wave (wc), fragment (ks,ct), lane l reads
//   Bp[((((y*8+kb)*2+ks)*8+wc*4+ct)*64+l)*8 .. +7]
// which equals Bw[n0 + wc*64+ct*16+(l&15)][kb*64+(ks*4+(l>>4))*8 + 0..7].
__global__ __launch_bounds__(256) void convert_weights(
    const float* __restrict__ wA, const float* __restrict__ wFc,
    const float* __restrict__ wGc, const float* __restrict__ wZ,
    const float* __restrict__ wFh,
    const float* __restrict__ bFc, const float* __restrict__ bGc,
    const float* __restrict__ bZ,  const float* __restrict__ bFh,
    unsigned short* __restrict__ WA, unsigned short* __restrict__ Wall,
    float* __restrict__ biasP)
{
  int idx = blockIdx.x*256 + threadIdx.x;      // < 656384
  if (idx >= 655360){
    int j = idx - 655360;                      // 0..1023
    int mat = j >> 8, jj = j & 255;
    const float* bp = (mat == 0) ? bFc : (mat == 1) ? bGc : (mat == 2) ? bZ : bFh;
    biasP[j] = bp[jj];
    return;
  }
  int m = idx >> 17;                           // 131072 = 2^17
  int i = idx & 131071;
  float v;
  if      (m == 0) v = wA[i];
  else if (m == 1) v = wFc[i];
  else if (m == 2) v = wGc[i];
  else if (m == 3) v = wZ[i];
  else             v = wFh[i];
  unsigned short o = f2b(v);

  int n   = (m == 0) ? (i >> 9) : ((m - 1)*256 + (i >> 9));
  int col = i & 511;
  int y  = n >> 7, nn = n & 127;
  int cb = nn >> 4, lr = nn & 15;
  int kb = col >> 6, c6 = col & 63;
  int ch = c6 >> 3, e = c6 & 7;
  int ks = ch >> 2, lq = ch & 3;
  int lane = lq*16 + lr;
  size_t pidx = ((((size_t)(y*8 + kb)*2 + ks)*8 + cb)*64 + lane)*8 + e;
  if (m == 0) WA[pidx] = o;
  else        Wall[pidx] = o;
}

// u (B,N,512) fp32 -> cB[r*256+q] bf16 (c part), hT[r*256+q] bf16 (h part), r=n*B+b
__global__ __launch_bounds__(256) void convert_u(
    const float* __restrict__ u, unsigned short* __restrict__ cB,
    unsigned short* __restrict__ hT)
{
  int r = blockIdx.x*4 + (threadIdx.x >> 6);
  int l = threadIdx.x & 63;
  int n = r >> 3, b = r & 7;
  const float* up = u + (size_t)(b*N_ + n)*512 + l*4;
  float4 cf = *(const float4*)up;
  float4 hf = *(const float4*)(up + 256);
  u16x4v c4, h4;
  c4.x = f2b(cf.x); c4.y = f2b(cf.y); c4.z = f2b(cf.z); c4.w = f2b(cf.w);
  h4.x = f2b(hf.x); h4.y = f2b(hf.y); h4.z = f2b(hf.z); h4.w = f2b(hf.w);
  *(u16x4v*)(cB + (size_t)r*256 + l*4) = c4;
  *(u16x4v*)(hT + (size_t)r*256 + l*4) = h4;
}

// ---------------- CSR build ----------------

__global__ __launch_bounds__(256) void hist_kernel(const int* __restrict__ dst, int* __restrict__ deg){
  int e = blockIdx.x*256 + threadIdx.x;   // exactly E_
  atomicAdd(&deg[dst[e]], 1);
}

__global__ __launch_bounds__(256) void scan_kernel(
    const int* __restrict__ deg, int* __restrict__ row_start, float* __restrict__ inv_deg)
{
  __shared__ int sums[256];
  int t = threadIdx.x;
  int base = t*20;
  int cnt[20];
  int local = 0;
#pragma unroll
  for (int i = 0; i < 20; ++i){
    int n = base + i;
    int d = (n < N_) ? deg[n] : 0;
    cnt[i] = d; local += d;
  }
  sums[t] = local; __syncthreads();
  for (int s = 1; s < 256; s <<= 1){
    int v = (t >= s) ? sums[t - s] : 0;
    __syncthreads();
    sums[t] += v;
    __syncthreads();
  }
  int prefix = (t == 0) ? 0 : sums[t-1];
#pragma unroll
  for (int i = 0; i < 20; ++i){
    int n = base + i;
    if (n < N_){
      row_start[n] = prefix;
      int d = cnt[i];
      inv_deg[n] = 1.0f / (float)((d > 1) ? d : 1);
      prefix += d;
    }
  }
  if (t == 255) row_start[N_] = prefix;
}

__global__ __launch_bounds__(256) void fill_kernel(
    const int* __restrict__ src, const int* __restrict__ dst,
    const int* __restrict__ row_start, int* __restrict__ cursor, int* __restrict__ csr)
{
  int e = blockIdx.x*256 + threadIdx.x;
  int d = dst[e];
  int p = atomicAdd(&cursor[d], 1);
  csr[row_start[d] + p] = src[e];
}

// ---------------- gather: batch-partitioned across XCDs ----------------
// Traffic fix: the old one-block-per-node gather read all 8 batches of hT per
// block, so every XCD's working set was the full 20.5 MB table -> per-XCD L2
// (4 MiB) missed ~40% -> 260 MB HBM fetch at the random-access BW floor.
// Now block id handles ONLY batch (id & 7); under round-robin dispatch all
// blocks of batch b land on XCD b (same mechanism as the GEMM's T1 swizzle),
// and the per-XCD working set is the 2.56 MB batch-slice of hT -> L2-resident.
// Each wave = one (batch, node): lanes 0-31 even edges, 32-63 odd edges,
// 16 B/lane (512 B per edge-slice), shfl_xor(32) merges the halves.
__global__ __launch_bounds__(256) void gather_bn_kernel(
    const unsigned short* __restrict__ hT, const int* __restrict__ csr,
    const int* __restrict__ row_start, const float* __restrict__ inv_deg,
    unsigned short* __restrict__ aggT)
{
  const int id = blockIdx.x;
  const int bb = id & 7;                    // batch -> XCD under round-robin
  const int g  = id >> 3;                   // node group (0..1249)
  const int tid = threadIdx.x;
  const int n = g*4 + (tid >> 6);           // this wave's node
  const int l = tid & 63;
  const int half = l >> 5, li = l & 31;
  const size_t coff = (size_t)bb*256 + li*8;
  const int e0 = row_start[n], e1 = row_start[n+1];

  float acc[8] = {};
  int e = e0;
  // 4 edges per iteration: two independent L2 loads in flight per lane.
  for (; e + 3 < e1; e += 4){
    const int s0 = csr[e + half];
    const int s1 = csr[e + 2 + half];
    u16x8v v0 = *(const u16x8v*)(hT + (size_t)s0*2048 + coff);
    u16x8v v1 = *(const u16x8v*)(hT + (size_t)s1*2048 + coff);
#pragma unroll
    for (int i = 0; i < 8; ++i) acc[i] += b2f(v0[i]) + b2f(v1[i]);
  }
  for (; e < e1; e += 2){
    const int idx = e + half;
    u16x8v v = {};
    if (idx < e1){
      const int s = csr[idx];
      v = *(const u16x8v*)(hT + (size_t)s*2048 + coff);
    }
#pragma unroll
    for (int i = 0; i < 8; ++i) acc[i] += b2f(v[i]);
  }
#pragma unroll
  for (int i = 0; i < 8; ++i) acc[i] += __shfl_xor(acc[i], 32, 64);

  if (half == 0){
    const float inv = inv_deg[n];
    u16x8v o;
#pragma unroll
    for (int i = 0; i < 8; ++i) o[i] = f2b(acc[i]*inv);
    *(u16x8v*)(aggT + (size_t)n*2048 + coff) = o;
  }
}

// ---------------- tiled GEMM (A via LDS dbuf, B direct-from-L2, counted vmcnt) ----
// C[m, n] = act( [A0|A1](m, 0:512) . Bw(n, 0:512) + bias[n] )
// 128x128 tile, 4 waves (2x2 of 64x64), BK=64.
// A: double-buffered global_load_lds (16 KB/step) with XOR-chunk swizzle on the
//    GLOBAL address; fragment ds_read_b128 bank-conflict-free. LDS = 34816 B.
// B: L2-resident (<=1 MB), loaded DIRECTLY into registers from the fragment-
//    packed layout (8 x 1KB coalesced wave loads per K-step), prefetched one
//    K-step ahead into ping-pong register arrays. No LDS, no barrier dep.
// Sync per K-step: issue 4 A-stages, fence, issue 8 B-prefetches, compute,
//    s_waitcnt vmcnt(8)  <- waits ONLY the 4 oldest (A-stages); the 8 B loads
//    stay in flight across the barrier (T4). sched_barrier(0) pins ds_reads
//    below the barrier (rule #18).
// MODE 0 (NY=2): gemm1 -> dst[r*256 + col], softplus.
// MODE 1 (NY=8): gemm_big -> act[(b*N+n)*1024 + col], tanh on slab y>>1==2.

__device__ __forceinline__ void stage_a(
    const unsigned short* __restrict__ As, int m0, int ak,
    int srow, int schunk, int w, unsigned short* lbuf)
{
#pragma unroll
  for (int i = 0; i < 4; ++i){
    const unsigned short* gp = As + (size_t)(m0 + i*32 + srow)*256 + ak + schunk*8;
    unsigned short* lp = lbuf + (i*32 + w*8)*64;
    __builtin_amdgcn_global_load_lds((const __attribute__((address_space(1))) void*)gp,
                                     (__attribute__((address_space(3))) void*)lp, 16, 0, 0);
  }
}

__device__ __forceinline__ void load_b(
    const unsigned short* __restrict__ Bp, int y, int kb, int wc, int l, v8bf (&b)[8])
{
#pragma unroll
  for (int ks = 0; ks < 2; ++ks)
#pragma unroll
    for (int ct = 0; ct < 4; ++ct)
      b[ks*4+ct] = *(const v8bf*)(Bp +
          ((((size_t)(y*8 + kb)*2 + ks)*8 + wc*4 + ct)*64 + l)*8);
}

__device__ __forceinline__ void compute_tile(
    const unsigned short* lA, int wr, int lq, int lr,
    const v8bf (&bb)[8], v4f (&acc)[4][4])
{
#pragma unroll
  for (int ks = 0; ks < 2; ++ks){
    v8bf a[4];
#pragma unroll
    for (int rt = 0; rt < 4; ++rt){
      const int ar = wr*64 + rt*16 + lr;
      a[rt] = *(const v8bf*)(lA + ar*64 + (((ks*4 + lq) ^ (ar & 7)))*8);
    }
#pragma unroll
    for (int rt = 0; rt < 4; ++rt)
#pragma unroll
      for (int ct = 0; ct < 4; ++ct)
        acc[rt][ct] = __builtin_amdgcn_mfma_f32_16x16x32_bf16(a[rt], bb[ks*4+ct], acc[rt][ct], 0, 0, 0);
  }
}

template<int MODE>
__global__ __launch_bounds__(256, 3) void gemm_tiled(
    const unsigned short* __restrict__ A0, const unsigned short* __restrict__ A1,
    const unsigned short* __restrict__ Bp, const float* __restrict__ bias,
    unsigned short* dstp)
{
  const int id = blockIdx.x;
  int x, y;
  if (MODE == 1){
    const int u6 = id & 63;
    y = u6 >> 3;
    x = (id >> 6)*8 + (u6 & 7);
  } else {
    const int u4 = id & 15;
    y = u4 >> 3;
    x = (id >> 4)*8 + (u4 & 7);
  }
  if (x >= XT_) return;

  // A staging dbuf: 2 x (128x64) bf16 = 32 KB; epilogue repack 128x136 = 34816 B.
  __shared__ unsigned short lds[17408];

  const int tid = threadIdx.x;
  const int w  = tid >> 6, l = tid & 63;
  const int wr = w >> 1,  wc = w & 1;
  const int lq = l >> 4,  lr = l & 15;
  const int m0 = x * 128;
  const int n0 = y * 128;

  // staging: per issue of 32 rows, thread covers row (tid>>3),
  // fetching global 16B chunk ((tid&7) ^ (row&7)) into LDS slot (tid&7).
  const int srow   = tid >> 3;                 // 0..31
  const int schunk = (tid & 7) ^ (srow & 7);   // swizzled k-chunk

  v4f acc[4][4] = {};
  v8bf b0[8], b1[8];

  // prologue: stage A(0) -> buf0 (issued FIRST = oldest 4 vmem), prefetch B(0).
  stage_a(A0, m0, 0, srow, schunk, w, lds);
  asm volatile("" ::: "memory");               // keep B loads after the stages
  load_b(Bp, y, 0, wc, l, b0);
  asm volatile("s_waitcnt vmcnt(8)" ::: "memory");  // A(0) landed; B(0) may fly
  __builtin_amdgcn_s_barrier();
  __builtin_amdgcn_sched_barrier(0);

#pragma unroll
  for (int kb = 0; kb < 7; ++kb){
    const int kn = kb + 1;
    stage_a((kn < 4) ? A0 : A1, m0, (kn & 3)*64, srow, schunk, w,
            lds + (kn & 1)*8192);
    asm volatile("" ::: "memory");             // keep B loads after the stages
    if (kn & 1) load_b(Bp, y, kn, wc, l, b1);
    else        load_b(Bp, y, kn, wc, l, b0);
    if (kb & 1) compute_tile(lds + 8192, wr, lq, lr, b1, acc);
    else        compute_tile(lds,        wr, lq, lr, b0, acc);
    // wait only the 4 A-stage loads (oldest); 8 B prefetches cross the barrier
    asm volatile("s_waitcnt vmcnt(8)" ::: "memory");
    __builtin_amdgcn_s_barrier();
    __builtin_amdgcn_sched_barrier(0);
  }
  compute_tile(lds + 8192, wr, lq, lr, b1, acc);   // kb=7: buf1, b1

  float bv[4];
#pragma unroll
  for (int ct = 0; ct < 4; ++ct) bv[ct] = bias[n0 + wc*64 + ct*16 + lr];

  const bool is_tanh = (MODE == 1) && ((y >> 1) == 2);

  __syncthreads();   // done reading lds; reuse as output repack buffer
#pragma unroll
  for (int rt = 0; rt < 4; ++rt){
#pragma unroll
    for (int ct = 0; ct < 4; ++ct){
      const int col = wc*64 + ct*16 + lr;
#pragma unroll
      for (int reg = 0; reg < 4; ++reg){
        const int row = wr*64 + rt*16 + lq*4 + reg;
        const float xv = acc[rt][ct][reg] + bv[ct];
        const float v = is_tanh ? tanh_(xv) : softplus_(xv);
        lds[row*136 + col] = f2b(v);
      }
    }
  }
  __syncthreads();

  // coalesced store: 8 issues, each row gets 16 lanes x 16B = 256B contiguous
#pragma unroll
  for (int i = 0; i < 8; ++i){
    const int row = i*16 + (tid >> 4);
    const int r = m0 + row;
    if (r < M_){
      const uint4 v = *(const uint4*)(lds + row*136 + (tid & 15)*8);
      if (MODE == 0){
        *(uint4*)(dstp + (size_t)r*256 + n0 + (tid & 15)*8) = v;
      } else {
        const int n = r >> 3, b = r & 7;
        *(uint4*)(dstp + ((size_t)b*N_ + n)*1024 + n0 + (tid & 15)*8) = v;
      }
    }
  }
}

// ---------------- epilogue: dc with projection + dh ----------------

__global__ __launch_bounds__(256) void epilogue_kernel(
    const unsigned short* act, const float* __restrict__ u, float* out)
{
  int r = blockIdx.x*4 + (threadIdx.x >> 6);
  int l = threadIdx.x & 63;
  int n = r >> 3, b = r & 7;
  const size_t rr = (size_t)(b*N_ + n);
  const unsigned short* arow = act + rr*1024;
  const float* urow = u + rr*512;
  float* orow = out + rr*512;

  u16x4v fc4 = *(const u16x4v*)(arow +        l*4);
  u16x4v gc4 = *(const u16x4v*)(arow + 256 +  l*4);
  u16x4v z4  = *(const u16x4v*)(arow + 512 +  l*4);
  u16x4v fh4 = *(const u16x4v*)(arow + 768 +  l*4);
  float4 c4f = *(const float4*)(urow + l*4);
  float4 h4f = *(const float4*)(urow + 256 + l*4);

  float c[4] = {c4f.x, c4f.y, c4f.z, c4f.w};
  float h[4] = {h4f.x, h4f.y, h4f.z, h4f.w};
  float dc[4], fh[4];
  float num = 0.f, den = 0.f;
#pragma unroll
  for (int i = 0; i < 4; ++i){
    float fc = b2f(fc4[i]), gc = b2f(gc4[i]), z = b2f(z4[i]);
    fh[i] = b2f(fh4[i]);
    dc[i] = -fc*c[i] + gc*z;
    num += dc[i]*c[i];
    den += c[i]*c[i];
  }
#pragma unroll
  for (int s = 1; s < 64; s <<= 1){
    num += __shfl_xor(num, s, 64);
    den += __shfl_xor(den, s, 64);
  }
  const float proj = num / den;

  float4 o, oh;
  o.x = dc[0] - proj*c[0]; o.y = dc[1] - proj*c[1];
  o.z = dc[2] - proj*c[2]; o.w = dc[3] - proj*c[3];
  oh.x = -fh[0]*h[0]; oh.y = -fh[1]*h[1];
  oh.z = -fh[2]*h[2]; oh.w = -fh[3]*h[3];
  *(float4*)(orow + l*4) = o;
  *(float4*)(orow + 256 + l*4) = oh;
}

// ---------------- launch ----------------

extern "C" void kernel_launch(void* const* d_in, const int* in_sizes, int n_in,
                              void* d_out, int out_size, void* d_ws, size_t ws_size,
                              hipStream_t stream) {
  const float* u    = (const float*)d_in[0];
  const int*   src  = (const int*)d_in[1];
  const int*   dst  = (const int*)d_in[2];
  const float* wFc  = (const float*)d_in[4];
  const float* bFc  = (const float*)d_in[5];
  const float* wFh  = (const float*)d_in[6];
  const float* bFh  = (const float*)d_in[7];
  const float* wGc  = (const float*)d_in[8];
  const float* bGc  = (const float*)d_in[9];
  const float* wZ   = (const float*)d_in[10];
  const float* bZ   = (const float*)d_in[11];
  const float* wA   = (const float*)d_in[12];
  const float* bA   = (const float*)d_in[13];
  float* out = (float*)d_out;
  unsigned short* act = (unsigned short*)d_out;   // bf16 activations overlay out

  // ws layout. GEMM A-staging over-reads up to 64 rows past the end of
  // hT/cB/aggT/hB — each overflow lands in the NEXT allocation (readable garbage,
  // results discarded by the r < M_ store guard). Keep this buffer order.
  char* W = (char*)d_ws;
  unsigned short* hT   = (unsigned short*)(W + 0);           // 20,480,000 B
  unsigned short* cB   = (unsigned short*)(W + 20480000);
  unsigned short* aggT = (unsigned short*)(W + 40960000);
  unsigned short* hB   = (unsigned short*)(W + 61440000);
  unsigned short* WA   = (unsigned short*)(W + 81920000);    // 262,144 B (packed)
  unsigned short* Wall = (unsigned short*)(W + 82182144);    // 1,048,576 B (packed)
  float* biasP   = (float*)(W + 83230720);                   // 4,096 B
  int* deg       = (int*)(W + 83234816);
  int* row_start = (int*)(W + 83255296);
  int* cursor    = (int*)(W + 83275776);
  int* csr       = (int*)(W + 83296256);                     // 640,000 B
  float* inv_deg = (float*)(W + 83936256);

  zero_int2<<<(N_ + 255)/256, 256, 0, stream>>>(deg, cursor, N_);
  convert_weights<<<2564, 256, 0, stream>>>(wA, wFc, wGc, wZ, wFh,
                                            bFc, bGc, bZ, bFh, WA, Wall, biasP);
  convert_u<<<M_/4, 256, 0, stream>>>(u, cB, hT);
  hist_kernel<<<E_/256, 256, 0, stream>>>(dst, deg);
  scan_kernel<<<1, 256, 0, stream>>>(deg, row_start, inv_deg);
  fill_kernel<<<E_/256, 256, 0, stream>>>(src, dst, row_start, cursor, csr);

  // batch-partitioned gather: id&7 = batch -> XCD; 1250 node-groups x 4 nodes
  gather_bn_kernel<<<8*1250, 256, 0, stream>>>(hT, csr, row_start, inv_deg, aggT);

  // 1-D swizzled grids: 40 g-groups of 8 x-tiles (x<313 guard inside)
  gemm_tiled<0><<<40*16, 256, 0, stream>>>(hT, aggT, WA, bA, hB);
  gemm_tiled<1><<<40*64, 256, 0, stream>>>(cB, hB, Wall, biasP, act);

  epilogue_kernel<<<M_/4, 256, 0, stream>>>(act, u, out);
}